// Round 9
// baseline (1266.353 us; speedup 1.0000x reference)
//
#include <hip/hip_runtime.h>
#include <hip/hip_fp16.h>

// RNAGNN round 8b: non-temporal streaming (protect z-table L2 residency), 1024-thread
// CSR-build kernels (occupancy), 4-deep gather unroll (MLP).
// Split-feature fp16 tables (3.2 MB -> one XCD L2), two gather passes per conv,
// fused matmul/BN/head epilogues.

#define DIM 16
#define F_IN 64
#define BUCK_SHIFT 10
#define BUCK_SIZE 1024
#define MAXB 256            // nb = ceil(200000/1024) = 196
#define BIN_CHUNK 16384

// LDS weight layout: W[f][j] at f*17+j -> lanes with distinct f hit distinct banks
#define WA_OFF 0
#define WB_OFF 272
#define BA_OFF 544
#define BB_OFF 560
#define SW_SIZE 576
#define WIDX(f, j) ((f) * 17 + (j))

// --- non-temporal helpers (builtin needs scalar / ext_vector_type, not HIP_vector_type)
typedef __attribute__((ext_vector_type(4))) float evf4;
typedef __attribute__((ext_vector_type(2))) float evf2;

__device__ __forceinline__ int ntload(const int* p) { return __builtin_nontemporal_load(p); }
__device__ __forceinline__ unsigned ntload(const unsigned* p) { return __builtin_nontemporal_load(p); }
__device__ __forceinline__ float ntload(const float* p) { return __builtin_nontemporal_load(p); }
__device__ __forceinline__ void ntstore(int* p, int v) { __builtin_nontemporal_store(v, p); }
__device__ __forceinline__ void ntstore(unsigned* p, unsigned v) { __builtin_nontemporal_store(v, p); }
__device__ __forceinline__ void ntstore(float* p, float v) { __builtin_nontemporal_store(v, p); }

__device__ __forceinline__ float4 ntload4(const float4* p) {
    evf4 v = __builtin_nontemporal_load((const evf4*)p);
    return make_float4(v.x, v.y, v.z, v.w);
}
__device__ __forceinline__ void ntstore4(float4* p, float4 v) {
    evf4 t; t.x = v.x; t.y = v.y; t.z = v.z; t.w = v.w;
    __builtin_nontemporal_store(t, (evf4*)p);
}
__device__ __forceinline__ float2 ntload2(const float2* p) {
    evf2 v = __builtin_nontemporal_load((const evf2*)p);
    return make_float2(v.x, v.y);
}
__device__ __forceinline__ void ntstore2(float2* p, float2 v) {
    evf2 t; t.x = v.x; t.y = v.y;
    __builtin_nontemporal_store(t, (evf2*)p);
}

// ---------------- per-bucket edge histogram ----------------

__launch_bounds__(1024)
__global__ void hist_kernel(const int* __restrict__ dst, int* __restrict__ ghist,
                            int E, int nb) {
    __shared__ int lh[MAXB];
    int t = threadIdx.x;
    for (int i = t; i < nb; i += 1024) lh[i] = 0;
    __syncthreads();
    int base = blockIdx.x * BIN_CHUNK;
    int end = min(base + BIN_CHUNK, E);
    for (int e = base + t; e < end; e += 1024) atomicAdd(&lh[ntload(dst + e) >> BUCK_SHIFT], 1);
    __syncthreads();
    for (int b = t; b < nb; b += 1024) {
        int c = lh[b];
        if (c) atomicAdd(&ghist[b], c);
    }
}

// exclusive scan of ghist (nb <= 256) -> boff, cursor
__global__ void scan_kernel(const int* __restrict__ ghist, int* __restrict__ boff,
                            int* __restrict__ cursor, int nb, int E) {
    __shared__ int sd[256];
    int t = threadIdx.x;
    int v = (t < nb) ? ghist[t] : 0;
    sd[t] = v;
    __syncthreads();
    for (int off = 1; off < 256; off <<= 1) {
        int u = (t >= off) ? sd[t - off] : 0;
        __syncthreads();
        sd[t] += u;
        __syncthreads();
    }
    if (t < nb) {
        int excl = sd[t] - v;
        boff[t] = excl;
        cursor[t] = excl;
    }
    if (t == 255) boff[nb] = E;
}

// pass A: bin edges into dst-range buckets; packed = src | (local_dst << 18)
__launch_bounds__(1024)
__global__ void bin_kernel(const int* __restrict__ src, const int* __restrict__ dst,
                           int* __restrict__ cursor, unsigned* __restrict__ packed,
                           int E, int nb) {
    __shared__ int lh[MAXB];
    int t = threadIdx.x;
    int base = blockIdx.x * BIN_CHUNK;
    int end = min(base + BIN_CHUNK, E);
    for (int i = t; i < nb; i += 1024) lh[i] = 0;
    __syncthreads();
    for (int e = base + t; e < end; e += 1024) atomicAdd(&lh[ntload(dst + e) >> BUCK_SHIFT], 1);
    __syncthreads();
    for (int b = t; b < nb; b += 1024) {
        int c = lh[b];
        lh[b] = c ? atomicAdd(&cursor[b], c) : 0;
    }
    __syncthreads();
    for (int e = base + t; e < end; e += 1024) {
        int d = ntload(dst + e);
        int s = ntload(src + e);
        int b = d >> BUCK_SHIFT;
        int pos = atomicAdd(&lh[b], 1);
        ntstore(packed + pos, (unsigned)s | ((unsigned)(d & (BUCK_SIZE - 1)) << 18));
    }
}

// pass B: bucket -> exact CSR; derives degree, rowptr (N+1), dinv. 1024 threads.
__launch_bounds__(1024)
__global__ void csr_kernel(const unsigned* __restrict__ packed, const int* __restrict__ boff,
                           int* __restrict__ rowptr, float* __restrict__ dinv,
                           int* __restrict__ col, int N, int E) {
    __shared__ int cnt[BUCK_SIZE];
    __shared__ int sd[BUCK_SIZE];
    __shared__ int scur[BUCK_SIZE];
    int t = threadIdx.x, blk = blockIdx.x;
    cnt[t] = 0;
    __syncthreads();
    int b0 = boff[blk], e1 = boff[blk + 1];
    for (int e = b0 + t; e < e1; e += 1024) atomicAdd(&cnt[ntload(packed + e) >> 18], 1);
    __syncthreads();
    int d = cnt[t];
    sd[t] = d;
    __syncthreads();
    for (int off = 1; off < 1024; off <<= 1) {
        int v = (t >= off) ? sd[t - off] : 0;
        __syncthreads();
        sd[t] += v;
        __syncthreads();
    }
    int start = b0 + sd[t] - d;
    int i = (blk << BUCK_SHIFT) + t;
    if (i < N) {
        ntstore(rowptr + i, start);
        ntstore(dinv + i, rsqrtf((float)(d + 1)));   // +1 = self loop
        if (i == N - 1) rowptr[N] = E;
    }
    scur[t] = start;
    __syncthreads();
    for (int e = b0 + t; e < e1; e += 1024) {
        unsigned k = ntload(packed + e);
        int pos = atomicAdd(&scur[k >> 18], 1);
        ntstore(col + pos, (int)(k & 0x3FFFFu));
    }
}

// ---------------- z0 = dinv * (x @ W_in), split fp16 tables ----------------

__global__ void z0_kernel(const float* __restrict__ x, const float* __restrict__ W,
                          const float* __restrict__ dinv,
                          __half* __restrict__ zlo, __half* __restrict__ zhi, int n) {
    __shared__ float sW[F_IN * DIM];
    int t = threadIdx.x;
#pragma unroll
    for (int j = 0; j < 4; ++j) sW[t + j * 256] = W[t + j * 256];
    __syncthreads();
    int idx = blockIdx.x * 256 + t;
    if (idx >= n * 2) return;
    int node = idx >> 1, p = idx & 1;
    float acc[8] = {0, 0, 0, 0, 0, 0, 0, 0};
    const float4* xr = (const float4*)(x + (size_t)node * F_IN);
#pragma unroll
    for (int k4 = 0; k4 < 16; ++k4) {
        float4 xv = ntload4(xr + k4);
        float c[4] = { xv.x, xv.y, xv.z, xv.w };
#pragma unroll
        for (int cc = 0; cc < 4; ++cc) {
            const float* wr = &sW[(k4 * 4 + cc) * DIM + p * 8];
#pragma unroll
            for (int j = 0; j < 8; ++j) acc[j] += c[cc] * wr[j];
        }
    }
    float di = dinv[node];
    __half2 o[4];
#pragma unroll
    for (int m = 0; m < 4; ++m) o[m] = __floats2half2_rn(di * acc[2 * m], di * acc[2 * m + 1]);
    __half* zt = p ? zhi : zlo;
    *(float4*)(zt + ((size_t)node << 3)) = *(float4*)o;
}

// ---------------- gather over one half-table (8 feats), 8 lanes/node ----------------
// MODE 10: store r (pass lo)
// MODE 0 : identity epilogue, znext = fp16(di*(r + b_slice))   (layer 0, per pass)
// MODE 1 : pass hi, full matmul -> o1 (pre-BN fp32) + BN partials -> bnsum replica
// MODE 3 : pass hi, dual matmul + ReLU -> o1, o2 (heads)

template <int MODE>
__launch_bounds__(256)
__global__ void gather8_kernel(const int* __restrict__ rowptr, const int* __restrict__ col,
                               const __half* __restrict__ zP, const float* __restrict__ dinv,
                               const float* __restrict__ rlo,
                               const float* __restrict__ Wa, const float* __restrict__ Wb,
                               const float* __restrict__ ba, const float* __restrict__ bb,
                               float* __restrict__ o1, float* __restrict__ o2,
                               __half* __restrict__ znext, float* __restrict__ rout,
                               float* __restrict__ bnsum, int N, int pass) {
    __shared__ float sW[SW_SIZE];
    __shared__ float sred[4][32];
    int t = threadIdx.x;
    if (MODE == 1 || MODE == 3) {
        int f = t >> 4, j = t & 15;
        sW[WA_OFF + WIDX(f, j)] = Wa[t];
        if (MODE == 3) sW[WB_OFF + WIDX(f, j)] = Wb[t];
        if (t < 16) {
            sW[BA_OFF + t] = ba[t];
            if (MODE == 3) sW[BB_OFF + t] = bb[t];
        }
        __syncthreads();
    } else if (MODE == 0) {
        if (t < 8) sW[BA_OFF + t] = ba[pass * 8 + t];
        __syncthreads();
    }

    int idx = blockIdx.x * 256 + t;
    int node = idx >> 3, o = idx & 7;          // 8 lanes per node
    bool alive = node < N;
    float a[8] = {0, 0, 0, 0, 0, 0, 0, 0};
    float di = 0.f;
    if (alive) {
        di = ntload(dinv + node);
        int start = ntload(rowptr + node);
        int len = ntload(rowptr + node + 1) - start;
        int k = o;
        for (; k + 24 < len; k += 32) {        // 4 edges in flight per lane
            int s0 = ntload(col + start + k);
            int s1 = ntload(col + start + k + 8);
            int s2 = ntload(col + start + k + 16);
            int s3 = ntload(col + start + k + 24);
            float4 v0 = *(const float4*)(zP + ((size_t)s0 << 3));
            float4 v1 = *(const float4*)(zP + ((size_t)s1 << 3));
            float4 v2 = *(const float4*)(zP + ((size_t)s2 << 3));
            float4 v3 = *(const float4*)(zP + ((size_t)s3 << 3));
            const __half2* h0 = (const __half2*)&v0;
            const __half2* h1 = (const __half2*)&v1;
            const __half2* h2 = (const __half2*)&v2;
            const __half2* h3 = (const __half2*)&v3;
#pragma unroll
            for (int m = 0; m < 4; ++m) {
                float2 f0 = __half22float2(h0[m]);
                float2 f1 = __half22float2(h1[m]);
                float2 f2 = __half22float2(h2[m]);
                float2 f3 = __half22float2(h3[m]);
                a[2 * m]     += (f0.x + f1.x) + (f2.x + f3.x);
                a[2 * m + 1] += (f0.y + f1.y) + (f2.y + f3.y);
            }
        }
        for (; k < len; k += 8) {
            int s = ntload(col + start + k);
            float4 v = *(const float4*)(zP + ((size_t)s << 3));
            const __half2* vh = (const __half2*)&v;
#pragma unroll
            for (int m = 0; m < 4; ++m) {
                float2 f2 = __half22float2(vh[m]);
                a[2 * m] += f2.x; a[2 * m + 1] += f2.y;
            }
        }
    }
#pragma unroll
    for (int j = 0; j < 8; ++j) {
        a[j] += __shfl_xor(a[j], 1);
        a[j] += __shfl_xor(a[j], 2);
        a[j] += __shfl_xor(a[j], 4);
    }
    if (alive) {   // self loop (all 8 lanes add same value -> consistent)
        float4 sv = *(const float4*)(zP + ((size_t)node << 3));
        const __half2* sh = (const __half2*)&sv;
#pragma unroll
        for (int m = 0; m < 4; ++m) {
            float2 f2 = __half22float2(sh[m]);
            a[2 * m] += f2.x; a[2 * m + 1] += f2.y;
        }
    }
    float r[8];
#pragma unroll
    for (int j = 0; j < 8; ++j) r[j] = di * a[j];

    if (MODE == 10) {
        if (alive && o < 2) {
            float4 w = (o == 0) ? make_float4(r[0], r[1], r[2], r[3])
                                : make_float4(r[4], r[5], r[6], r[7]);
            ntstore4((float4*)(rout + ((size_t)node << 3) + (o << 2)), w);
        }
        return;
    }
    if (MODE == 0) {
        if (alive && o == 0) {
            __half2 ov[4];
#pragma unroll
            for (int m = 0; m < 4; ++m)
                ov[m] = __floats2half2_rn(di * (r[2 * m] + sW[BA_OFF + 2 * m]),
                                          di * (r[2 * m + 1] + sW[BA_OFF + 2 * m + 1]));
            *(float4*)(znext + ((size_t)node << 3)) = *(float4*)ov;
        }
        return;
    }

    // MODE 1 / 3: lane o owns input feats {2o, 2o+1}; o<4 from rlo, o>=4 from local r
    float rc0, rc1;
    if (o < 4) {
        float2 v = alive ? ntload2((const float2*)(rlo + ((size_t)node << 3) + 2 * o))
                         : make_float2(0.f, 0.f);
        rc0 = v.x; rc1 = v.y;
    } else {
        rc0 = r[2 * (o - 4)]; rc1 = r[2 * (o - 4) + 1];
        if (!alive) { rc0 = 0.f; rc1 = 0.f; }
    }
    int f0 = 2 * o;
    float pa[16];
#pragma unroll
    for (int j = 0; j < 16; ++j)
        pa[j] = rc0 * sW[WA_OFF + WIDX(f0, j)] + rc1 * sW[WA_OFF + WIDX(f0 + 1, j)];
#pragma unroll
    for (int j = 0; j < 16; ++j) {
        pa[j] += __shfl_xor(pa[j], 1);
        pa[j] += __shfl_xor(pa[j], 2);
        pa[j] += __shfl_xor(pa[j], 4);
    }

    if (MODE == 1) {
        float o0 = pa[2 * o] + sW[BA_OFF + 2 * o];
        float o1v = pa[2 * o + 1] + sW[BA_OFF + 2 * o + 1];
        if (alive)
            ntstore2((float2*)(o1 + ((size_t)node << 4) + 2 * o), make_float2(o0, o1v));
        float s0 = alive ? o0 : 0.f, s1 = alive ? o1v : 0.f;
        float q0 = s0 * s0, q1 = s1 * s1;
#pragma unroll
        for (int m = 8; m <= 32; m <<= 1) {
            s0 += __shfl_xor(s0, m); s1 += __shfl_xor(s1, m);
            q0 += __shfl_xor(q0, m); q1 += __shfl_xor(q1, m);
        }
        int lane = t & 63, wave = t >> 6;
        if (lane < 8) {
            sred[wave][2 * lane] = s0;
            sred[wave][2 * lane + 1] = s1;
            sred[wave][16 + 2 * lane] = q0;
            sred[wave][16 + 2 * lane + 1] = q1;
        }
        __syncthreads();
        if (t < 32) {
            float v = sred[0][t] + sred[1][t] + sred[2][t] + sred[3][t];
            atomicAdd(&bnsum[(blockIdx.x & 7) * 32 + t], v);
        }
        return;
    }

    // MODE 3: dual heads
    {
        float pb[16];
#pragma unroll
        for (int j = 0; j < 16; ++j)
            pb[j] = rc0 * sW[WB_OFF + WIDX(f0, j)] + rc1 * sW[WB_OFF + WIDX(f0 + 1, j)];
#pragma unroll
        for (int j = 0; j < 16; ++j) {
            pb[j] += __shfl_xor(pb[j], 1);
            pb[j] += __shfl_xor(pb[j], 2);
            pb[j] += __shfl_xor(pb[j], 4);
        }
        if (alive) {
            float oa0 = fmaxf(pa[2 * o] + sW[BA_OFF + 2 * o], 0.f);
            float oa1 = fmaxf(pa[2 * o + 1] + sW[BA_OFF + 2 * o + 1], 0.f);
            float ob0 = fmaxf(pb[2 * o] + sW[BB_OFF + 2 * o], 0.f);
            float ob1 = fmaxf(pb[2 * o + 1] + sW[BB_OFF + 2 * o + 1], 0.f);
            ntstore2((float2*)(o1 + ((size_t)node << 4) + 2 * o), make_float2(oa0, oa1));
            ntstore2((float2*)(o2 + ((size_t)node << 4) + 2 * o), make_float2(ob0, ob1));
        }
    }
}

// ---------------- BN finalize (8 replicas -> scale/shift) ----------------

__global__ void bnfin_kernel(const float* __restrict__ bnsum, const float* __restrict__ gamma,
                             const float* __restrict__ beta, float* __restrict__ ssout, int n) {
    int t = threadIdx.x;
    if (t >= 16) return;
    float s = 0.f, sq = 0.f;
#pragma unroll
    for (int rep = 0; rep < 8; ++rep) {
        s += bnsum[rep * 32 + t];
        sq += bnsum[rep * 32 + 16 + t];
    }
    float invN = 1.f / (float)n;
    float mean = s * invN;
    float var = fmaxf(sq * invN - mean * mean, 0.f);
    float scale = gamma[t] * rsqrtf(var + 1e-5f);
    ssout[t] = scale;
    ssout[16 + t] = beta[t] - mean * scale;
}

// ---------------- BN apply + ReLU -> next split z tables ----------------

__global__ void bn_relu_z_kernel(const float* __restrict__ hp, const float* __restrict__ ss,
                                 const float* __restrict__ dinv,
                                 __half* __restrict__ zlo, __half* __restrict__ zhi, int n) {
    int idx = blockIdx.x * 256 + threadIdx.x;
    if (idx >= n * 2) return;
    int node = idx >> 1, p = idx & 1;
    float di = dinv[node];
    const float4* hr = (const float4*)(hp + ((size_t)node << 4) + p * 8);
    float4 v0 = ntload4(hr), v1 = ntload4(hr + 1);
    float vv[8] = { v0.x, v0.y, v0.z, v0.w, v1.x, v1.y, v1.z, v1.w };
    __half2 o[4];
#pragma unroll
    for (int m = 0; m < 4; ++m) {
        int f0 = p * 8 + 2 * m;
        float r0 = di * fmaxf(vv[2 * m] * ss[f0] + ss[16 + f0], 0.f);
        float r1 = di * fmaxf(vv[2 * m + 1] * ss[f0 + 1] + ss[16 + f0 + 1], 0.f);
        o[m] = __floats2half2_rn(r0, r1);
    }
    __half* zt = p ? zhi : zlo;
    *(float4*)(zt + ((size_t)node << 3)) = *(float4*)o;
}

// ---------------- launcher ----------------

extern "C" void kernel_launch(void* const* d_in, const int* in_sizes, int n_in,
                              void* d_out, int out_size, void* d_ws, size_t ws_size,
                              hipStream_t stream) {
    (void)n_in; (void)out_size; (void)ws_size;
    const float* x      = (const float*)d_in[0];
    const int*   edge   = (const int*)d_in[1];
    const float* W_in   = (const float*)d_in[2];
    const float* b_in   = (const float*)d_in[3];
    const float* Ws     = (const float*)d_in[4];
    const float* bs     = (const float*)d_in[5];
    const float* gammas = (const float*)d_in[6];
    const float* betas  = (const float*)d_in[7];
    const float* W_sin  = (const float*)d_in[8];
    const float* b_sin  = (const float*)d_in[9];
    const float* W_cos  = (const float*)d_in[10];
    const float* b_cos  = (const float*)d_in[11];
    float* out = (float*)d_out;

    const int N = in_sizes[0] / F_IN;          // 200000
    const int E = in_sizes[1] / 2;             // 6400000
    const int L = in_sizes[4] / (DIM * DIM);   // 4
    const int nb = (N + BUCK_SIZE - 1) >> BUCK_SHIFT;   // 196
    const int* src = edge;
    const int* dst = edge + E;

    char* ws = (char*)d_ws;
    size_t off = 0;
    auto alloc = [&](size_t bytes) { char* p = ws + off; off += (bytes + 15) & ~size_t(15); return p; };
    float*    dinv   = (float*)alloc((size_t)N * 4);
    int*      ghist  = (int*)alloc((size_t)nb * 4);
    int*      boff   = (int*)alloc((size_t)(nb + 1) * 4);
    int*      cursor = (int*)alloc((size_t)nb * 4);
    int*      rowptr = (int*)alloc((size_t)(N + 1) * 4);
    unsigned* packed = (unsigned*)alloc((size_t)E * 4);
    int*      col    = (int*)alloc((size_t)E * 4);
    __half*   zAlo   = (__half*)alloc((size_t)N * 8 * 2);
    __half*   zAhi   = (__half*)alloc((size_t)N * 8 * 2);
    __half*   zBlo   = (__half*)alloc((size_t)N * 8 * 2);
    __half*   zBhi   = (__half*)alloc((size_t)N * 8 * 2);
    float*    rbuf   = (float*)alloc((size_t)N * 8 * 4);
    float*    hp     = (float*)alloc((size_t)N * DIM * 4);
    float*    bnsum  = (float*)alloc((size_t)L * 256 * 4);   // 8 replicas x 32 per layer
    float*    ssbuf  = (float*)alloc((size_t)L * 32 * 4);

    hipMemsetAsync(ghist, 0, (size_t)nb * 4, stream);
    hipMemsetAsync(bnsum, 0, (size_t)L * 256 * 4, stream);

    const int nchunk = (E + BIN_CHUNK - 1) / BIN_CHUNK;
    hist_kernel<<<nchunk, 1024, 0, stream>>>(dst, ghist, E, nb);
    scan_kernel<<<1, 256, 0, stream>>>(ghist, boff, cursor, nb, E);
    bin_kernel<<<nchunk, 1024, 0, stream>>>(src, dst, cursor, packed, E, nb);
    csr_kernel<<<nb, 1024, 0, stream>>>(packed, boff, rowptr, dinv, col, N, E);

    const int G = (N * 8 + 255) / 256;         // gather grid (8 lanes/node)

    // layer 0: z0 then identity-epilogue passes (halves independent)
    z0_kernel<<<(N * 2 + 255) / 256, 256, 0, stream>>>(x, W_in, dinv, zAlo, zAhi, N);
    gather8_kernel<0><<<G, 256, 0, stream>>>(rowptr, col, zAlo, dinv, nullptr,
                                             nullptr, nullptr, b_in, nullptr,
                                             nullptr, nullptr, zBlo, nullptr, nullptr, N, 0);
    gather8_kernel<0><<<G, 256, 0, stream>>>(rowptr, col, zAhi, dinv, nullptr,
                                             nullptr, nullptr, b_in, nullptr,
                                             nullptr, nullptr, zBhi, nullptr, nullptr, N, 1);
    __half *clo = zBlo, *chi = zBhi, *nlo = zAlo, *nhi = zAhi;

    for (int l = 0; l < L; ++l) {
        gather8_kernel<10><<<G, 256, 0, stream>>>(rowptr, col, clo, dinv, nullptr,
                                                  nullptr, nullptr, nullptr, nullptr,
                                                  nullptr, nullptr, nullptr, rbuf, nullptr, N, 0);
        gather8_kernel<1><<<G, 256, 0, stream>>>(rowptr, col, chi, dinv, rbuf,
                                                 Ws + l * DIM * DIM, nullptr,
                                                 bs + l * DIM, nullptr,
                                                 hp, nullptr, nullptr, nullptr,
                                                 bnsum + l * 256, N, 1);
        bnfin_kernel<<<1, 64, 0, stream>>>(bnsum + l * 256, gammas + l * DIM,
                                           betas + l * DIM, ssbuf + l * 32, N);
        bn_relu_z_kernel<<<(N * 2 + 255) / 256, 256, 0, stream>>>(hp, ssbuf + l * 32, dinv,
                                                                  nlo, nhi, N);
        __half* t1 = clo; clo = nlo; nlo = t1;
        __half* t2 = chi; chi = nhi; nhi = t2;
    }

    // heads: shared aggregation, dual epilogue into d_out
    gather8_kernel<10><<<G, 256, 0, stream>>>(rowptr, col, clo, dinv, nullptr,
                                              nullptr, nullptr, nullptr, nullptr,
                                              nullptr, nullptr, nullptr, rbuf, nullptr, N, 0);
    gather8_kernel<3><<<G, 256, 0, stream>>>(rowptr, col, chi, dinv, rbuf,
                                             W_sin, W_cos, b_sin, b_cos,
                                             out, out + (size_t)N * DIM, nullptr, nullptr,
                                             nullptr, N, 1);
}